// Round 13
// baseline (141.743 us; speedup 1.0000x reference)
//
#include <hip/hip_runtime.h>

#define IN_F 1024
#define OUT_F 1024
#define NNZ 16384

typedef _Float16 f16;
typedef _Float16 f16x4 __attribute__((ext_vector_type(4)));
typedef _Float16 f16x8 __attribute__((ext_vector_type(8)));
typedef float f32x4 __attribute__((ext_vector_type(4)));
typedef unsigned short ushort8 __attribute__((ext_vector_type(8)));

#define AS1 __attribute__((address_space(1)))
#define AS3 __attribute__((address_space(3)))

// ---------------------------------------------------------------------------
// Workspace: Wl = LINEAR W_eff (f16, 2 MiB) @0; mode flag @2MiB; Xs @2MiB+4096.
// Xs staged layout (quarters): qidx = g2*16 + kt (g2 = 64-row group, kt =
// 64-K tile) = [64 rows][64 k] = 512 slots x 16B; slot u = r*8 + bb holds
// X[g2*64+r][kt*64 + ((bb^(r&7))<<3) .. +8]  (128B-stride 8-way-XOR, 0-conflict).
// B (W_eff) is NOT LDS-staged: fragments read straight from Wl (L2-hot, 2MB)
// into registers, prefetched one half-tile ahead.
//
// SYNC INVARIANT (r9): DMA-staged LDS is written by ALL waves; vmcnt drains
// only the issuing wave's loads -> every cross-wave read of a staged buffer
// must be preceded by VMW(n) -> s_barrier.
// ---------------------------------------------------------------------------

__global__ void detect_mode(const unsigned short* __restrict__ w, int* __restrict__ mode) {
  __shared__ float smax[256];
  __shared__ int semax[256];
  int t = threadIdx.x;
  const float* wf = (const float*)w;
  float m32 = fabsf(wf[t]);
  m32 = fmaxf(m32, fabsf(wf[t + 256]));
  int e8 = 0;
#pragma unroll
  for (int j = 0; j < 8; ++j) {
    unsigned short u = w[t * 8 + j];
    int e = (u >> 7) & 0xFF;
    e8 = e > e8 ? e : e8;
  }
  smax[t] = m32; semax[t] = e8;
  __syncthreads();
  for (int s = 128; s > 0; s >>= 1) {
    if (t < s) {
      smax[t] = fmaxf(smax[t], smax[t + s]);
      semax[t] = semax[t] > semax[t + s] ? semax[t] : semax[t + s];
    }
    __syncthreads();
  }
  if (t == 0) {
    int m;
    if (!(smax[0] > 1e-6f)) m = 2;        // native f16
    else if (semax[0] >= 140) m = 0;      // f32 (upcast from fp16)
    else m = 1;                           // bf16
    *mode = m;
  }
}

__device__ __forceinline__ float load_w(const void* base, size_t i, int mode) {
  if (mode == 0) return ((const float*)base)[i];
  if (mode == 1) {
    unsigned int u = (unsigned int)((const unsigned short*)base)[i] << 16;
    return __uint_as_float(u);
  }
  return (float)((const f16*)base)[i];
}

// Linear copy: W_eff base (cast to f16) -> Wl.
__global__ void prep_base(const void* __restrict__ base, f16* __restrict__ Wl,
                          const int* __restrict__ modep) {
  int mode = *modep;
  int id = blockIdx.x * 256 + threadIdx.x;   // 8-f16 chunk id, 131072 total
  size_t off = (size_t)id * 8;
  f16x8 h;
  if (mode == 0) {
    const float* b = (const float*)base + off;
    float4 v0 = *reinterpret_cast<const float4*>(b);
    float4 v1 = *reinterpret_cast<const float4*>(b + 4);
    h = (f16x8){(f16)v0.x, (f16)v0.y, (f16)v0.z, (f16)v0.w,
                (f16)v1.x, (f16)v1.y, (f16)v1.z, (f16)v1.w};
  } else if (mode == 1) {
    ushort8 uv = *reinterpret_cast<const ushort8*>((const unsigned short*)base + off);
#pragma unroll
    for (int j = 0; j < 8; ++j)
      h[j] = (f16)__uint_as_float((unsigned int)uv[j] << 16);
  } else {
    h = *reinterpret_cast<const f16x8*>((const f16*)base + off);
  }
  *reinterpret_cast<f16x8*>(Wl + off) = h;
}

__global__ void prep_scatter(const void* __restrict__ base,
                             const void* __restrict__ vals,
                             const int* __restrict__ idx,
                             const float* __restrict__ alpha,
                             f16* __restrict__ Wl,
                             const int* __restrict__ modep) {
  int mode = *modep;
  int i = blockIdx.x * 256 + threadIdx.x;
  if (i >= NNZ) return;
  int id = idx[i];
  float v = load_w(base, id, mode) + alpha[0] * load_w(vals, i, mode);
  Wl[id] = (f16)v;
}

// conv_x v3 (proven r10/r11): thread unit = one staged 16B slot -> stores
// fully contiguous; loads are 32B pieces permuted within a 256B row segment.
__global__ void __launch_bounds__(256) conv_x(const float* __restrict__ X,
                                              f16* __restrict__ Xs, int total) {
  int stride = gridDim.x * 256;
  for (int id = blockIdx.x * 256 + threadIdx.x; id < total; id += stride) {
    int u = id & 511;
    int qidx = id >> 9;
    int kt = qidx & 15;
    int g2 = qidx >> 4;
    int r = u >> 3, bb = u & 7;
    int b = bb ^ (r & 7);
    size_t row = (size_t)g2 * 64 + r;
    const float* p = X + row * IN_F + kt * 64 + b * 8;
    float4 v0 = *reinterpret_cast<const float4*>(p);
    float4 v1 = *reinterpret_cast<const float4*>(p + 4);
    f16x8 h = {(f16)v0.x, (f16)v0.y, (f16)v0.z, (f16)v0.w,
               (f16)v1.x, (f16)v1.y, (f16)v1.z, (f16)v1.w};
    *reinterpret_cast<f16x8*>(Xs + (size_t)id * 8) = h;   // contiguous
  }
}

#define SB0 __builtin_amdgcn_sched_barrier(0)
#define VMW(N) asm volatile("s_waitcnt vmcnt(" #N ")" ::: "memory")

// ---------------------------------------------------------------------------
// gemm9: 256x256, BK=64, 512 thr (8 waves 2Mx4N), wave tile 128x64.
// A: LDS-staged (DMA, quarters, proven swizzle), 64 KiB double-buffered.
// B: register-direct from linear Wl (L2-hot), prefetched one half-tile ahead
//    (bC holds current k-half, bN the next; fixed roles, no swap).
// Per tile (2 fat phases, 2 barriers):
//  gate: [issue A(KT+1)x4] -> VMW(12) (drains A(KT); 12 = Bg8 + newA4) ->
//        s_barrier (RAW, r9 invariant)
//  ph0:  ds_read A(S0) 8xb128; load bN <- B(KT,S1) global; lgkm(0); 32 MFMA(bC)
//  ph1:  ds_read A(S1); [load bC <- B(KT+1,S0)]; lgkm(0); 32 MFMA(bN)
//  end:  s_barrier (WAR)
// vmcnt never 0 in main loop; B-reg waits are compiler-counted.
// ---------------------------------------------------------------------------

#define ISSUE_QA(QI, KT1, PB)                                                  \
    __builtin_amdgcn_global_load_lds(                                          \
        (const AS1 void*)(Xs + ((size_t)((mt * 4 + (QI)) * 16 + (KT1))) * 4096 + t * 8), \
        (AS3 void*)(&sA[((PB) * 4 + (QI)) * 4096 + t * 8]), 16, 0, 0)

#define DSREAD_A(P, S_) do {                                                   \
    _Pragma("unroll")                                                          \
    for (int qq_ = 0; qq_ < 2; ++qq_) {                                        \
      int qa_ = ((P) * 4 + wm * 2 + qq_) * 4096;                               \
      _Pragma("unroll")                                                        \
      for (int mf_ = 0; mf_ < 4; ++mf_) {                                      \
        int r_ = mf_ * 16 + lr;                                                \
        int blk_ = ((S_) * 4 + lk) ^ (lr & 7);                                 \
        afr[qq_][mf_] = *reinterpret_cast<const f16x8*>(&sA[qa_ + r_ * 64 + blk_ * 8]); \
      }                                                                        \
    }                                                                          \
  } while (0)

// B fragments for k-half S_ of tile KT, straight from linear Wl into DST.
#define LOAD_BG(DST, KT, S_) do {                                              \
    const f16* bp_ = Wl + (size_t)(nt * 256 + wn * 64 + lr) * IN_F             \
                     + (KT) * 64 + (S_) * 32 + lk * 8;                         \
    _Pragma("unroll")                                                          \
    for (int nf_ = 0; nf_ < 4; ++nf_)                                          \
      DST[nf_] = *reinterpret_cast<const f16x8*>(bp_ + (size_t)nf_ * 16 * IN_F); \
  } while (0)

#define MFMA32B(BARR) do {                                                     \
    asm volatile("s_waitcnt lgkmcnt(0)" ::: "memory");                         \
    SB0;                                                                       \
    __builtin_amdgcn_s_setprio(1);                                             \
    _Pragma("unroll")                                                          \
    for (int qq_ = 0; qq_ < 2; ++qq_)                                          \
      _Pragma("unroll")                                                        \
      for (int mf_ = 0; mf_ < 4; ++mf_)                                        \
        _Pragma("unroll")                                                      \
        for (int nf_ = 0; nf_ < 4; ++nf_)                                      \
          acc[qq_ * 4 + mf_][nf_] = __builtin_amdgcn_mfma_f32_16x16x32_f16(    \
              afr[qq_][mf_], BARR[nf_], acc[qq_ * 4 + mf_][nf_], 0, 0, 0);     \
    __builtin_amdgcn_s_setprio(0);                                             \
  } while (0)

#define KTILE9(P, KT, PREF) do {                                               \
    if (PREF) { ISSUE_QA(0, (KT) + 1, (P) ^ 1); ISSUE_QA(1, (KT) + 1, (P) ^ 1);\
                ISSUE_QA(2, (KT) + 1, (P) ^ 1); ISSUE_QA(3, (KT) + 1, (P) ^ 1);\
                SB0; VMW(12); }                                                \
    else { VMW(0); }                                                           \
    SB0;                                                                       \
    __builtin_amdgcn_s_barrier();   /* RAW gate: A buffer P resident */        \
    SB0;                                                                       \
    DSREAD_A(P, 0);                                                            \
    SB0;                                                                       \
    LOAD_BG(bN, KT, 1);             /* B(KT,S1) -> regs (used ph1) */          \
    SB0;                                                                       \
    MFMA32B(bC);                                                               \
    /* ---- ph1 (S=1) ---- */                                                  \
    DSREAD_A(P, 1);                                                            \
    SB0;                                                                       \
    if (PREF) { LOAD_BG(bC, (KT) + 1, 0); }  /* B(KT+1,S0) */                  \
    SB0;                                                                       \
    MFMA32B(bN);                                                               \
    SB0;                                                                       \
    __builtin_amdgcn_s_barrier();   /* WAR gate: A reads of P complete */      \
    SB0;                                                                       \
  } while (0)

__global__ void __launch_bounds__(512, 2) gemm9(const f16* __restrict__ Xs,
                                                const f16* __restrict__ Wl,
                                                float* __restrict__ C) {
  extern __shared__ f16 lds[];
  f16* sA = lds;            // [2buf][4 quarters][4096] = 64 KiB

  int bidx = blockIdx.x;
  int q = gridDim.x >> 3;
  int wg = (bidx & 7) * q + (bidx >> 3);
  int mt = wg >> 2, nt = wg & 3;

  int t = threadIdx.x;
  int lane = t & 63;
  int w = t >> 6;
  int wm = w >> 2;           // M half (128 rows) -> A quarters 2wm, 2wm+1
  int wn = w & 3;            // N quarter (64 cols)
  int lr = lane & 15;
  int lk = lane >> 4;

  f16x8 afr[2][4], bC[4], bN[4];
  f32x4 acc[8][4];
#pragma unroll
  for (int i = 0; i < 8; ++i)
#pragma unroll
    for (int j = 0; j < 4; ++j)
      acc[i][j] = (f32x4){0.f, 0.f, 0.f, 0.f};

  // prologue: DMA A tile0 -> buf0; bC <- B(0,S0); full drain + barrier
  ISSUE_QA(0, 0, 0); ISSUE_QA(1, 0, 0); ISSUE_QA(2, 0, 0); ISSUE_QA(3, 0, 0);
  SB0;
  LOAD_BG(bC, 0, 0);
  SB0;
  VMW(0);
  __builtin_amdgcn_s_barrier();
  SB0;

  for (int kt2 = 0; kt2 < 14; kt2 += 2) {
    KTILE9(0, kt2, true);
    KTILE9(1, kt2 + 1, true);
  }
  KTILE9(0, 14, true);
  KTILE9(1, 15, false);

  // epilogue: D layout col = lane&15, row = (lane>>4)*4 + reg
  float* Cw = C + (size_t)(mt * 256 + wm * 128 + lk * 4) * OUT_F + nt * 256 + wn * 64 + lr;
#pragma unroll
  for (int m = 0; m < 8; ++m) {
    int rowo = (m >> 2) * 64 + (m & 3) * 16;
#pragma unroll
    for (int nf = 0; nf < 4; ++nf)
#pragma unroll
      for (int g = 0; g < 4; ++g)
        Cw[(size_t)(rowo + g) * OUT_F + nf * 16] = acc[m][nf][g];
  }
}

extern "C" void kernel_launch(void* const* d_in, const int* in_sizes, int n_in,
                              void* d_out, int out_size, void* d_ws, size_t ws_size,
                              hipStream_t stream) {
  const float* X = (const float*)d_in[0];
  const void* base = d_in[1];
  const void* vals = d_in[2];
  const int* idx = (const int*)d_in[3];
  const float* alpha = (const float*)d_in[4];
  float* out = (float*)d_out;
  f16* Wl = (f16*)d_ws;                                   // linear W_eff
  int* modep = (int*)((char*)d_ws + 2 * 1024 * 1024);
  f16* Xs = (f16*)((char*)d_ws + 2 * 1024 * 1024 + 4096);

  int M = in_sizes[0] / IN_F;              // 32768
  int total = (M * IN_F) / 8;              // staged 16B slots

  (void)hipFuncSetAttribute(reinterpret_cast<const void*>(&gemm9),
                            hipFuncAttributeMaxDynamicSharedMemorySize, 65536);

  detect_mode<<<dim3(1), dim3(256), 0, stream>>>((const unsigned short*)base, modep);
  prep_base<<<dim3(512), dim3(256), 0, stream>>>(base, Wl, modep);
  prep_scatter<<<dim3((NNZ + 255) / 256), dim3(256), 0, stream>>>(base, vals, idx, alpha, Wl, modep);
  conv_x<<<dim3(2048), dim3(256), 0, stream>>>(X, Xs, total);
  gemm9<<<dim3((M / 256) * 4), dim3(512), 65536, stream>>>(Xs, Wl, out);
}

// Round 14
// 126.875 us; speedup vs baseline: 1.1172x; 1.1172x over previous
//
#include <hip/hip_runtime.h>

#define IN_F 1024
#define OUT_F 1024
#define NNZ 16384

typedef _Float16 f16;
typedef _Float16 f16x4 __attribute__((ext_vector_type(4)));
typedef _Float16 f16x8 __attribute__((ext_vector_type(8)));
typedef float f32x4 __attribute__((ext_vector_type(4)));
typedef unsigned short ushort8 __attribute__((ext_vector_type(8)));

#define AS1 __attribute__((address_space(1)))
#define AS3 __attribute__((address_space(3)))

// ---------------------------------------------------------------------------
// Workspace: Wl = LINEAR W_eff (f16, 2 MiB) @0; mode flag @2MiB; Xs (LINEAR
// f16 X, 64 MiB) @2MiB+4096.
// The MFMA swizzle no longer lives in memory: the GEMM's global_load_lds
// SOURCE addresses are pre-swizzled per lane (m173 trick) -- lane slot u
// (0..511 per 64x64 quarter): r=u>>3, bb=u&7 reads element block (bb^(r&7))
// of row r. LDS dest is linear, ds_reads apply the same XOR (G21 both-sides).
//
// SYNC INVARIANT (r9): DMA-staged LDS is written by ALL waves; vmcnt drains
// only the issuing wave's loads -> every cross-wave read of a staged buffer
// must be preceded by VMW(n) -> s_barrier.
// ---------------------------------------------------------------------------

__global__ void detect_mode(const unsigned short* __restrict__ w, int* __restrict__ mode) {
  __shared__ float smax[256];
  __shared__ int semax[256];
  int t = threadIdx.x;
  const float* wf = (const float*)w;
  float m32 = fabsf(wf[t]);
  m32 = fmaxf(m32, fabsf(wf[t + 256]));
  int e8 = 0;
#pragma unroll
  for (int j = 0; j < 8; ++j) {
    unsigned short u = w[t * 8 + j];
    int e = (u >> 7) & 0xFF;
    e8 = e > e8 ? e : e8;
  }
  smax[t] = m32; semax[t] = e8;
  __syncthreads();
  for (int s = 128; s > 0; s >>= 1) {
    if (t < s) {
      smax[t] = fmaxf(smax[t], smax[t + s]);
      semax[t] = semax[t] > semax[t + s] ? semax[t] : semax[t + s];
    }
    __syncthreads();
  }
  if (t == 0) {
    int m;
    if (!(smax[0] > 1e-6f)) m = 2;        // native f16
    else if (semax[0] >= 140) m = 0;      // f32 (upcast from fp16)
    else m = 1;                           // bf16
    *mode = m;
  }
}

__device__ __forceinline__ float load_w(const void* base, size_t i, int mode) {
  if (mode == 0) return ((const float*)base)[i];
  if (mode == 1) {
    unsigned int u = (unsigned int)((const unsigned short*)base)[i] << 16;
    return __uint_as_float(u);
  }
  return (float)((const f16*)base)[i];
}

// Linear cvt copy: W_eff base -> Wl (f16).
__global__ void prep_base(const void* __restrict__ base, f16* __restrict__ Wl,
                          const int* __restrict__ modep) {
  int mode = *modep;
  int id = blockIdx.x * 256 + threadIdx.x;   // 8-f16 chunk id, 131072 total
  size_t off = (size_t)id * 8;
  f16x8 h;
  if (mode == 0) {
    const float* b = (const float*)base + off;
    float4 v0 = *reinterpret_cast<const float4*>(b);
    float4 v1 = *reinterpret_cast<const float4*>(b + 4);
    h = (f16x8){(f16)v0.x, (f16)v0.y, (f16)v0.z, (f16)v0.w,
                (f16)v1.x, (f16)v1.y, (f16)v1.z, (f16)v1.w};
  } else if (mode == 1) {
    ushort8 uv = *reinterpret_cast<const ushort8*>((const unsigned short*)base + off);
#pragma unroll
    for (int j = 0; j < 8; ++j)
      h[j] = (f16)__uint_as_float((unsigned int)uv[j] << 16);
  } else {
    h = *reinterpret_cast<const f16x8*>((const f16*)base + off);
  }
  *reinterpret_cast<f16x8*>(Wl + off) = h;
}

__global__ void prep_scatter(const void* __restrict__ base,
                             const void* __restrict__ vals,
                             const int* __restrict__ idx,
                             const float* __restrict__ alpha,
                             f16* __restrict__ Wl,
                             const int* __restrict__ modep) {
  int mode = *modep;
  int i = blockIdx.x * 256 + threadIdx.x;
  if (i >= NNZ) return;
  int id = idx[i];
  float v = load_w(base, id, mode) + alpha[0] * load_w(vals, i, mode);
  Wl[id] = (f16)v;
}

// conv_x v5: pure linear cvt copy -- both sides perfectly coalesced.
__global__ void __launch_bounds__(256) conv_x(const float* __restrict__ X,
                                              f16* __restrict__ Xs, int total) {
  int stride = gridDim.x * 256;
  for (int id = blockIdx.x * 256 + threadIdx.x; id < total; id += stride) {
    size_t off = (size_t)id * 8;
    const float* p = X + off;
    float4 v0 = *reinterpret_cast<const float4*>(p);
    float4 v1 = *reinterpret_cast<const float4*>(p + 4);
    f16x8 h = {(f16)v0.x, (f16)v0.y, (f16)v0.z, (f16)v0.w,
               (f16)v1.x, (f16)v1.y, (f16)v1.z, (f16)v1.w};
    *reinterpret_cast<f16x8*>(Xs + off) = h;
  }
}

#define SB0 __builtin_amdgcn_sched_barrier(0)
#define VMW(N) asm volatile("s_waitcnt vmcnt(" #N ")" ::: "memory")

// ---------------------------------------------------------------------------
// gemm10: gemm5's replay-proven skeleton (r10: 76 us, 0 conflicts), sources
// linear. 256x256, BK=64, 512 thr (8 waves 2Mx4N), wave tile 128x64.
// LDS 128 KiB: sA/sB = [2buf][4 row-quarters][64][64] f16, swizzle applied
// via per-lane DMA source offsets (linear dest) + XOR on ds_read.
// Per tile: ph0 {issue A(KT+1)x4 -> VMW(4) -> barrier(RAW) -> ds_read S0 ->
// issue B(KT+1)x4 -> lgkm(0) -> 32 MFMA}; ph1 {ds_read S1 -> lgkm(0) ->
// 32 MFMA -> barrier(WAR)}. vmcnt trace: steady VMW(4) drains prior tile's
// A+B (oldest 8), keeps new A in flight; VMW(0) only prologue/final tile.
// ---------------------------------------------------------------------------

#define ISSUE_QA(QI, KT1, PB)                                                  \
    __builtin_amdgcn_global_load_lds(                                          \
        (const AS1 void*)(Xs + rowOffA[QI] + (KT1) * 64 + swzc),               \
        (AS3 void*)(&sA[((PB) * 4 + (QI)) * 4096 + t * 8]), 16, 0, 0)

#define ISSUE_QB(QI, KT1, PB)                                                  \
    __builtin_amdgcn_global_load_lds(                                          \
        (const AS1 void*)(Wl + rowOffB[QI] + (KT1) * 64 + swzc),               \
        (AS3 void*)(&sB[((PB) * 4 + (QI)) * 4096 + t * 8]), 16, 0, 0)

#define DSREAD(P, S_) do {                                                     \
    _Pragma("unroll")                                                          \
    for (int qq_ = 0; qq_ < 2; ++qq_) {                                        \
      int qa_ = ((P) * 4 + wm * 2 + qq_) * 4096;                               \
      _Pragma("unroll")                                                        \
      for (int mf_ = 0; mf_ < 4; ++mf_) {                                      \
        int r_ = mf_ * 16 + lr;                                                \
        int blk_ = ((S_) * 4 + lk) ^ (lr & 7);                                 \
        afr[qq_][mf_] = *reinterpret_cast<const f16x8*>(&sA[qa_ + r_ * 64 + blk_ * 8]); \
      }                                                                        \
    }                                                                          \
    int qb_ = ((P) * 4 + wn) * 4096;                                           \
    _Pragma("unroll")                                                          \
    for (int nf_ = 0; nf_ < 4; ++nf_) {                                        \
      int r_ = nf_ * 16 + lr;                                                  \
      int blk_ = ((S_) * 4 + lk) ^ (lr & 7);                                   \
      bfr[nf_] = *reinterpret_cast<const f16x8*>(&sB[qb_ + r_ * 64 + blk_ * 8]); \
    }                                                                          \
  } while (0)

#define MFMA32(S_) do {                                                        \
    asm volatile("s_waitcnt lgkmcnt(0)" ::: "memory");                         \
    SB0;                                                                       \
    __builtin_amdgcn_s_setprio(1);                                             \
    _Pragma("unroll")                                                          \
    for (int qq_ = 0; qq_ < 2; ++qq_)                                          \
      _Pragma("unroll")                                                        \
      for (int mf_ = 0; mf_ < 4; ++mf_)                                        \
        _Pragma("unroll")                                                      \
        for (int nf_ = 0; nf_ < 4; ++nf_)                                      \
          acc[qq_ * 4 + mf_][nf_] = __builtin_amdgcn_mfma_f32_16x16x32_f16(    \
              afr[qq_][mf_], bfr[nf_], acc[qq_ * 4 + mf_][nf_], 0, 0, 0);      \
    __builtin_amdgcn_s_setprio(0);                                             \
  } while (0)

#define KTILE10(P, KT, PREF) do {                                              \
    /* ---- ph0 (S=0) ---- */                                                  \
    if (PREF) { ISSUE_QA(0, (KT) + 1, (P) ^ 1); ISSUE_QA(1, (KT) + 1, (P) ^ 1);\
                ISSUE_QA(2, (KT) + 1, (P) ^ 1); ISSUE_QA(3, (KT) + 1, (P) ^ 1);\
                SB0; VMW(4); }                                                 \
    else { VMW(0); }                                                           \
    SB0;                                                                       \
    __builtin_amdgcn_s_barrier();   /* RAW gate: buffer P fully resident */    \
    SB0;                                                                       \
    DSREAD(P, 0);                                                              \
    if (PREF) { SB0; ISSUE_QB(0, (KT) + 1, (P) ^ 1); ISSUE_QB(1, (KT) + 1, (P) ^ 1);\
                ISSUE_QB(2, (KT) + 1, (P) ^ 1); ISSUE_QB(3, (KT) + 1, (P) ^ 1); } \
    MFMA32(0);                                                                 \
    /* ---- ph1 (S=1) ---- */                                                  \
    DSREAD(P, 1);                                                              \
    MFMA32(1);                                                                 \
    SB0;                                                                       \
    __builtin_amdgcn_s_barrier();   /* WAR gate: reads of P complete */        \
    SB0;                                                                       \
  } while (0)

__global__ void __launch_bounds__(512, 2) gemm10(const f16* __restrict__ Xs,
                                                 const f16* __restrict__ Wl,
                                                 float* __restrict__ C) {
  extern __shared__ f16 lds[];
  f16* sA = lds;            // [2buf][4 quarters][4096]
  f16* sB = lds + 32768;

  int bidx = blockIdx.x;
  int q = gridDim.x >> 3;
  int wg = (bidx & 7) * q + (bidx >> 3);
  int mt = wg >> 2, nt = wg & 3;

  int t = threadIdx.x;
  int lane = t & 63;
  int w = t >> 6;
  int wm = w >> 2;           // M half (128 rows) -> A quarters 2wm, 2wm+1
  int wn = w & 3;            // N quarter (64 cols) == B row-quarter
  int lr = lane & 15;
  int lk = lane >> 4;

  // pre-swizzled DMA source geometry: slot u = t -> row r, col block bb^(r&7)
  int rS = t >> 3;
  int swzc = (((t & 7) ^ (rS & 7)) << 3);
  size_t rowOffA[4], rowOffB[4];
#pragma unroll
  for (int qi = 0; qi < 4; ++qi) {
    rowOffA[qi] = (size_t)(mt * 256 + qi * 64 + rS) * IN_F;
    rowOffB[qi] = (size_t)(nt * 256 + qi * 64 + rS) * IN_F;
  }

  f16x8 afr[2][4], bfr[4];
  f32x4 acc[8][4];
#pragma unroll
  for (int i = 0; i < 8; ++i)
#pragma unroll
    for (int j = 0; j < 4; ++j)
      acc[i][j] = (f32x4){0.f, 0.f, 0.f, 0.f};

  // prologue: DMA tile 0 -> buf0; full drain + barrier (r9 invariant)
  ISSUE_QA(0, 0, 0); ISSUE_QA(1, 0, 0); ISSUE_QA(2, 0, 0); ISSUE_QA(3, 0, 0);
  ISSUE_QB(0, 0, 0); ISSUE_QB(1, 0, 0); ISSUE_QB(2, 0, 0); ISSUE_QB(3, 0, 0);
  VMW(0);
  __builtin_amdgcn_s_barrier();
  SB0;

  for (int kt2 = 0; kt2 < 14; kt2 += 2) {
    KTILE10(0, kt2, true);
    KTILE10(1, kt2 + 1, true);
  }
  KTILE10(0, 14, true);
  KTILE10(1, 15, false);

  // epilogue: D layout col = lane&15, row = (lane>>4)*4 + reg
  float* Cw = C + (size_t)(mt * 256 + wm * 128 + lk * 4) * OUT_F + nt * 256 + wn * 64 + lr;
#pragma unroll
  for (int m = 0; m < 8; ++m) {
    int rowo = (m >> 2) * 64 + (m & 3) * 16;
#pragma unroll
    for (int nf = 0; nf < 4; ++nf)
#pragma unroll
      for (int g = 0; g < 4; ++g)
        Cw[(size_t)(rowo + g) * OUT_F + nf * 16] = acc[m][nf][g];
  }
}

extern "C" void kernel_launch(void* const* d_in, const int* in_sizes, int n_in,
                              void* d_out, int out_size, void* d_ws, size_t ws_size,
                              hipStream_t stream) {
  const float* X = (const float*)d_in[0];
  const void* base = d_in[1];
  const void* vals = d_in[2];
  const int* idx = (const int*)d_in[3];
  const float* alpha = (const float*)d_in[4];
  float* out = (float*)d_out;
  f16* Wl = (f16*)d_ws;                                   // linear W_eff
  int* modep = (int*)((char*)d_ws + 2 * 1024 * 1024);
  f16* Xs = (f16*)((char*)d_ws + 2 * 1024 * 1024 + 4096); // linear f16 X

  int M = in_sizes[0] / IN_F;              // 32768
  int total = (M * IN_F) / 8;              // 8-f16 chunks

  (void)hipFuncSetAttribute(reinterpret_cast<const void*>(&gemm10),
                            hipFuncAttributeMaxDynamicSharedMemorySize, 131072);

  detect_mode<<<dim3(1), dim3(256), 0, stream>>>((const unsigned short*)base, modep);
  prep_base<<<dim3(512), dim3(256), 0, stream>>>(base, Wl, modep);
  prep_scatter<<<dim3((NNZ + 255) / 256), dim3(256), 0, stream>>>(base, vals, idx, alpha, Wl, modep);
  conv_x<<<dim3(2048), dim3(256), 0, stream>>>(X, Xs, total);
  gemm10<<<dim3((M / 256) * 4), dim3(512), 131072, stream>>>(Xs, Wl, out);
}

// Round 15
// 121.141 us; speedup vs baseline: 1.1701x; 1.0473x over previous
//
#include <hip/hip_runtime.h>

#define IN_F 1024
#define OUT_F 1024
#define NNZ 16384

typedef _Float16 f16;
typedef _Float16 f16x4 __attribute__((ext_vector_type(4)));
typedef _Float16 f16x8 __attribute__((ext_vector_type(8)));
typedef float f32x4 __attribute__((ext_vector_type(4)));
typedef unsigned short ushort8 __attribute__((ext_vector_type(8)));

#define AS1 __attribute__((address_space(1)))
#define AS3 __attribute__((address_space(3)))

// ---------------------------------------------------------------------------
// Workspace: Wl = LINEAR W_eff (f16, 2 MiB) @0; Xs (LINEAR f16 X) @2MiB+4096.
// Swizzle lives in the DMA source address (m173): lane slot u: r=u>>3, bb=u&7
// reads block (bb^(r&7)) of row r; LDS dest linear; ds_read applies same XOR.
// SYNC INVARIANT (r9): DMA-staged LDS is written by ALL waves; vmcnt drains
// only the issuing wave's loads -> VMW(n) -> s_barrier before cross-wave read.
// ---------------------------------------------------------------------------

// Per-block weight-dtype detection (all blocks compute the same answer).
// 0 = f32-upcast, 1 = bf16, 2 = native f16.
__device__ __forceinline__ int compute_mode(const unsigned short* __restrict__ w,
                                            float* smax, int* semax) {
  int t = threadIdx.x;
  const float* wf = (const float*)w;
  float m32 = fmaxf(fabsf(wf[t]), fabsf(wf[t + 256]));
  int e8 = 0;
#pragma unroll
  for (int j = 0; j < 8; ++j) {
    unsigned short u = w[t * 8 + j];
    int e = (u >> 7) & 0xFF;
    e8 = e > e8 ? e : e8;
  }
  smax[t] = m32; semax[t] = e8;
  __syncthreads();
  for (int s = 128; s > 0; s >>= 1) {
    if (t < s) {
      smax[t] = fmaxf(smax[t], smax[t + s]);
      semax[t] = semax[t] > semax[t + s] ? semax[t] : semax[t + s];
    }
    __syncthreads();
  }
  int m;
  if (!(smax[0] > 1e-6f)) m = 2;
  else if (semax[0] >= 140) m = 0;
  else m = 1;
  return m;
}

__device__ __forceinline__ float load_w(const void* base, size_t i, int mode) {
  if (mode == 0) return ((const float*)base)[i];
  if (mode == 1) {
    unsigned int u = (unsigned int)((const unsigned short*)base)[i] << 16;
    return __uint_as_float(u);
  }
  return (float)((const f16*)base)[i];
}

// Linear cvt copy: W_eff base -> Wl (f16). Mode detected inline.
__global__ void prep_base(const void* __restrict__ base, f16* __restrict__ Wl) {
  __shared__ float smax[256];
  __shared__ int semax[256];
  int mode = compute_mode((const unsigned short*)base, smax, semax);
  int id = blockIdx.x * 256 + threadIdx.x;
  size_t off = (size_t)id * 8;
  f16x8 h;
  if (mode == 0) {
    const float* b = (const float*)base + off;
    float4 v0 = *reinterpret_cast<const float4*>(b);
    float4 v1 = *reinterpret_cast<const float4*>(b + 4);
    h = (f16x8){(f16)v0.x, (f16)v0.y, (f16)v0.z, (f16)v0.w,
                (f16)v1.x, (f16)v1.y, (f16)v1.z, (f16)v1.w};
  } else if (mode == 1) {
    ushort8 uv = *reinterpret_cast<const ushort8*>((const unsigned short*)base + off);
#pragma unroll
    for (int j = 0; j < 8; ++j)
      h[j] = (f16)__uint_as_float((unsigned int)uv[j] << 16);
  } else {
    h = *reinterpret_cast<const f16x8*>((const f16*)base + off);
  }
  *reinterpret_cast<f16x8*>(Wl + off) = h;
}

__global__ void prep_scatter(const void* __restrict__ base,
                             const void* __restrict__ vals,
                             const int* __restrict__ idx,
                             const float* __restrict__ alpha,
                             f16* __restrict__ Wl) {
  __shared__ float smax[256];
  __shared__ int semax[256];
  int mode = compute_mode((const unsigned short*)base, smax, semax);
  int i = blockIdx.x * 256 + threadIdx.x;
  if (i >= NNZ) return;
  int id = idx[i];
  float v = load_w(base, id, mode) + alpha[0] * load_w(vals, i, mode);
  Wl[id] = (f16)v;
}

// conv_x v5: pure linear cvt copy -- both sides perfectly coalesced.
__global__ void __launch_bounds__(256) conv_x(const float* __restrict__ X,
                                              f16* __restrict__ Xs, int total) {
  int stride = gridDim.x * 256;
  for (int id = blockIdx.x * 256 + threadIdx.x; id < total; id += stride) {
    size_t off = (size_t)id * 8;
    const float* p = X + off;
    float4 v0 = *reinterpret_cast<const float4*>(p);
    float4 v1 = *reinterpret_cast<const float4*>(p + 4);
    f16x8 h = {(f16)v0.x, (f16)v0.y, (f16)v0.z, (f16)v0.w,
               (f16)v1.x, (f16)v1.y, (f16)v1.z, (f16)v1.w};
    *reinterpret_cast<f16x8*>(Xs + off) = h;
  }
}

#define SB0 __builtin_amdgcn_sched_barrier(0)
#define VMW(N) asm volatile("s_waitcnt vmcnt(" #N ")" ::: "memory")

// ---------------------------------------------------------------------------
// gemm11: SINGLE-barrier K-loop. 256x256, BK=64, 512 thr (8 waves 2Mx4N),
// wave tile 128x64. LDS 160 KiB: A TRIPLE-buffered (3 x 32 KiB), B double
// (2 x 32 KiB). Issue schedule: QB(KT+1) at S0, QA(KT+2) at S1 (distance-2).
// End of tile KT: VMW(4) drains {QA(KT+1), QB(KT+1)} (oldest 8), keeps
// QA(KT+2) in flight; ONE s_barrier = WAR gate for this tile's buffers AND
// RAW gate for tile KT+1's (r9 invariant: VMW precedes barrier).
// WAR audit: QA(KT+2) targets A[(KT+2)%3] = A[(KT-1)%3], last read in tile
// KT-1, which completed before the barrier that started tile KT. QB(KT+1)
// targets B[(KT-1)%2], same argument. VMW(0) only at kt=14.
// ---------------------------------------------------------------------------

#define ISSUE_QA11(QI, KT1, AP)                                                \
    __builtin_amdgcn_global_load_lds(                                          \
        (const AS1 void*)(Xs + rowOffA[QI] + (KT1) * 64 + swzc),               \
        (AS3 void*)(&sA[((AP) * 4 + (QI)) * 4096 + t * 8]), 16, 0, 0)

#define ISSUE_QB11(QI, KT1, BP)                                                \
    __builtin_amdgcn_global_load_lds(                                          \
        (const AS1 void*)(Wl + rowOffB[QI] + (KT1) * 64 + swzc),               \
        (AS3 void*)(&sB[((BP) * 4 + (QI)) * 4096 + t * 8]), 16, 0, 0)

#define DSREAD11(AP, BP, S_) do {                                              \
    _Pragma("unroll")                                                          \
    for (int qq_ = 0; qq_ < 2; ++qq_) {                                        \
      int qa_ = ((AP) * 4 + wm * 2 + qq_) * 4096;                              \
      _Pragma("unroll")                                                        \
      for (int mf_ = 0; mf_ < 4; ++mf_) {                                      \
        int r_ = mf_ * 16 + lr;                                                \
        int blk_ = ((S_) * 4 + lk) ^ (lr & 7);                                 \
        afr[qq_][mf_] = *reinterpret_cast<const f16x8*>(&sA[qa_ + r_ * 64 + blk_ * 8]); \
      }                                                                        \
    }                                                                          \
    int qb_ = ((BP) * 4 + wn) * 4096;                                          \
    _Pragma("unroll")                                                          \
    for (int nf_ = 0; nf_ < 4; ++nf_) {                                        \
      int r_ = nf_ * 16 + lr;                                                  \
      int blk_ = ((S_) * 4 + lk) ^ (lr & 7);                                   \
      bfr[nf_] = *reinterpret_cast<const f16x8*>(&sB[qb_ + r_ * 64 + blk_ * 8]); \
    }                                                                          \
  } while (0)

#define MFMA32_11 do {                                                         \
    asm volatile("s_waitcnt lgkmcnt(0)" ::: "memory");                         \
    SB0;                                                                       \
    __builtin_amdgcn_s_setprio(1);                                             \
    _Pragma("unroll")                                                          \
    for (int qq_ = 0; qq_ < 2; ++qq_)                                          \
      _Pragma("unroll")                                                        \
      for (int mf_ = 0; mf_ < 4; ++mf_)                                        \
        _Pragma("unroll")                                                      \
        for (int nf_ = 0; nf_ < 4; ++nf_)                                      \
          acc[qq_ * 4 + mf_][nf_] = __builtin_amdgcn_mfma_f32_16x16x32_f16(    \
              afr[qq_][mf_], bfr[nf_], acc[qq_ * 4 + mf_][nf_], 0, 0, 0);      \
    __builtin_amdgcn_s_setprio(0);                                             \
  } while (0)

// ISSB: issue QB(KT+1) into B[(KT+1)%2]. ISSA: issue QA(KT+2) into A[(KT+2)%3].
#define KTILE11(AP, BP, KT, ISSB, ISSA, VMN, LASTBAR) do {                     \
    DSREAD11(AP, BP, 0);                                                       \
    if (ISSB) { SB0;                                                           \
      ISSUE_QB11(0, (KT) + 1, ((KT) + 1) & 1); ISSUE_QB11(1, (KT) + 1, ((KT) + 1) & 1); \
      ISSUE_QB11(2, (KT) + 1, ((KT) + 1) & 1); ISSUE_QB11(3, (KT) + 1, ((KT) + 1) & 1); } \
    MFMA32_11;                                                                 \
    DSREAD11(AP, BP, 1);                                                       \
    if (ISSA) { SB0;                                                           \
      ISSUE_QA11(0, (KT) + 2, ((KT) + 2) % 3); ISSUE_QA11(1, (KT) + 2, ((KT) + 2) % 3); \
      ISSUE_QA11(2, (KT) + 2, ((KT) + 2) % 3); ISSUE_QA11(3, (KT) + 2, ((KT) + 2) % 3); } \
    MFMA32_11;                                                                 \
    if (LASTBAR) {                                                             \
      SB0; VMW(VMN); SB0;                                                      \
      __builtin_amdgcn_s_barrier();  /* WAR(this) + RAW(next), r9 */           \
      SB0;                                                                     \
    }                                                                          \
  } while (0)

__global__ void __launch_bounds__(512, 2) gemm11(const f16* __restrict__ Xs,
                                                 const f16* __restrict__ Wl,
                                                 float* __restrict__ C) {
  extern __shared__ f16 lds[];
  f16* sA = lds;              // 3 bufs x [4 quarters][4096] = 96 KiB
  f16* sB = lds + 49152;      // 2 bufs x [4 quarters][4096] = 64 KiB

  int bidx = blockIdx.x;
  int q = gridDim.x >> 3;
  int wg = (bidx & 7) * q + (bidx >> 3);
  int mt = wg >> 2, nt = wg & 3;

  int t = threadIdx.x;
  int lane = t & 63;
  int w = t >> 6;
  int wm = w >> 2;
  int wn = w & 3;
  int lr = lane & 15;
  int lk = lane >> 4;

  int rS = t >> 3;
  int swzc = (((t & 7) ^ (rS & 7)) << 3);
  size_t rowOffA[4], rowOffB[4];
#pragma unroll
  for (int qi = 0; qi < 4; ++qi) {
    rowOffA[qi] = (size_t)(mt * 256 + qi * 64 + rS) * IN_F;
    rowOffB[qi] = (size_t)(nt * 256 + qi * 64 + rS) * IN_F;
  }

  f16x8 afr[2][4], bfr[4];
  f32x4 acc[8][4];
#pragma unroll
  for (int i = 0; i < 8; ++i)
#pragma unroll
    for (int j = 0; j < 4; ++j)
      acc[i][j] = (f32x4){0.f, 0.f, 0.f, 0.f};

  // prologue: QA(0)->A0, QB(0)->B0, QA(1)->A1; VMW(4) (drains A0,B0; QA1 in
  // flight); barrier (r9).
  ISSUE_QA11(0, 0, 0); ISSUE_QA11(1, 0, 0); ISSUE_QA11(2, 0, 0); ISSUE_QA11(3, 0, 0);
  ISSUE_QB11(0, 0, 0); ISSUE_QB11(1, 0, 0); ISSUE_QB11(2, 0, 0); ISSUE_QB11(3, 0, 0);
  ISSUE_QA11(0, 1, 1); ISSUE_QA11(1, 1, 1); ISSUE_QA11(2, 1, 1); ISSUE_QA11(3, 1, 1);
  SB0; VMW(4); SB0;
  __builtin_amdgcn_s_barrier();
  SB0;

  KTILE11(0, 0,  0, true,  true,  4, true);
  KTILE11(1, 1,  1, true,  true,  4, true);
  KTILE11(2, 0,  2, true,  true,  4, true);
  KTILE11(0, 1,  3, true,  true,  4, true);
  KTILE11(1, 0,  4, true,  true,  4, true);
  KTILE11(2, 1,  5, true,  true,  4, true);
  KTILE11(0, 0,  6, true,  true,  4, true);
  KTILE11(1, 1,  7, true,  true,  4, true);
  KTILE11(2, 0,  8, true,  true,  4, true);
  KTILE11(0, 1,  9, true,  true,  4, true);
  KTILE11(1, 0, 10, true,  true,  4, true);
  KTILE11(2, 1, 11, true,  true,  4, true);
  KTILE11(0, 0, 12, true,  true,  4, true);
  KTILE11(1, 1, 13, true,  true,  4, true);
  KTILE11(2, 0, 14, true,  false, 0, true);
  KTILE11(0, 1, 15, false, false, 0, false);

  float* Cw = C + (size_t)(mt * 256 + wm * 128 + lk * 4) * OUT_F + nt * 256 + wn * 64 + lr;
#pragma unroll
  for (int m = 0; m < 8; ++m) {
    int rowo = (m >> 2) * 64 + (m & 3) * 16;
#pragma unroll
    for (int nf = 0; nf < 4; ++nf)
#pragma unroll
      for (int g = 0; g < 4; ++g)
        Cw[(size_t)(rowo + g) * OUT_F + nf * 16] = acc[m][nf][g];
  }
}

// ---------------------------------------------------------------------------
// gemm10 fallback (replay-proven r14, 77 us): used if 160 KiB LDS rejected.
// ---------------------------------------------------------------------------

#define ISSUE_QA(QI, KT1, PB)                                                  \
    __builtin_amdgcn_global_load_lds(                                          \
        (const AS1 void*)(Xs + rowOffA[QI] + (KT1) * 64 + swzc),               \
        (AS3 void*)(&sA[((PB) * 4 + (QI)) * 4096 + t * 8]), 16, 0, 0)

#define ISSUE_QB(QI, KT1, PB)                                                  \
    __builtin_amdgcn_global_load_lds(                                          \
        (const AS1 void*)(Wl + rowOffB[QI] + (KT1) * 64 + swzc),               \
        (AS3 void*)(&sB[((PB) * 4 + (QI)) * 4096 + t * 8]), 16, 0, 0)

#define KTILE10(P, KT, PREF) do {                                              \
    if (PREF) { ISSUE_QA(0, (KT) + 1, (P) ^ 1); ISSUE_QA(1, (KT) + 1, (P) ^ 1);\
                ISSUE_QA(2, (KT) + 1, (P) ^ 1); ISSUE_QA(3, (KT) + 1, (P) ^ 1);\
                SB0; VMW(4); }                                                 \
    else { VMW(0); }                                                           \
    SB0;                                                                       \
    __builtin_amdgcn_s_barrier();                                              \
    SB0;                                                                       \
    DSREAD11(P, P, 0);                                                         \
    if (PREF) { SB0; ISSUE_QB(0, (KT) + 1, (P) ^ 1); ISSUE_QB(1, (KT) + 1, (P) ^ 1);\
                ISSUE_QB(2, (KT) + 1, (P) ^ 1); ISSUE_QB(3, (KT) + 1, (P) ^ 1); } \
    MFMA32_11;                                                                 \
    DSREAD11(P, P, 1);                                                         \
    MFMA32_11;                                                                 \
    SB0;                                                                       \
    __builtin_amdgcn_s_barrier();                                              \
    SB0;                                                                       \
  } while (0)

__global__ void __launch_bounds__(512, 2) gemm10(const f16* __restrict__ Xs,
                                                 const f16* __restrict__ Wl,
                                                 float* __restrict__ C) {
  extern __shared__ f16 lds[];
  f16* sA = lds;
  f16* sB = lds + 32768;

  int bidx = blockIdx.x;
  int q = gridDim.x >> 3;
  int wg = (bidx & 7) * q + (bidx >> 3);
  int mt = wg >> 2, nt = wg & 3;

  int t = threadIdx.x;
  int lane = t & 63;
  int w = t >> 6;
  int wm = w >> 2;
  int wn = w & 3;
  int lr = lane & 15;
  int lk = lane >> 4;

  int rS = t >> 3;
  int swzc = (((t & 7) ^ (rS & 7)) << 3);
  size_t rowOffA[4], rowOffB[4];
#pragma unroll
  for (int qi = 0; qi < 4; ++qi) {
    rowOffA[qi] = (size_t)(mt * 256 + qi * 64 + rS) * IN_F;
    rowOffB[qi] = (size_t)(nt * 256 + qi * 64 + rS) * IN_F;
  }

  f16x8 afr[2][4], bfr[4];
  f32x4 acc[8][4];
#pragma unroll
  for (int i = 0; i < 8; ++i)
#pragma unroll
    for (int j = 0; j < 4; ++j)
      acc[i][j] = (f32x4){0.f, 0.f, 0.f, 0.f};

  ISSUE_QA(0, 0, 0); ISSUE_QA(1, 0, 0); ISSUE_QA(2, 0, 0); ISSUE_QA(3, 0, 0);
  ISSUE_QB(0, 0, 0); ISSUE_QB(1, 0, 0); ISSUE_QB(2, 0, 0); ISSUE_QB(3, 0, 0);
  VMW(0);
  __builtin_amdgcn_s_barrier();
  SB0;

  for (int kt2 = 0; kt2 < 14; kt2 += 2) {
    KTILE10(0, kt2, true);
    KTILE10(1, kt2 + 1, true);
  }
  KTILE10(0, 14, true);
  KTILE10(1, 15, false);

  float* Cw = C + (size_t)(mt * 256 + wm * 128 + lk * 4) * OUT_F + nt * 256 + wn * 64 + lr;
#pragma unroll
  for (int m = 0; m < 8; ++m) {
    int rowo = (m >> 2) * 64 + (m & 3) * 16;
#pragma unroll
    for (int nf = 0; nf < 4; ++nf)
#pragma unroll
      for (int g = 0; g < 4; ++g)
        Cw[(size_t)(rowo + g) * OUT_F + nf * 16] = acc[m][nf][g];
  }
}

extern "C" void kernel_launch(void* const* d_in, const int* in_sizes, int n_in,
                              void* d_out, int out_size, void* d_ws, size_t ws_size,
                              hipStream_t stream) {
  const float* X = (const float*)d_in[0];
  const void* base = d_in[1];
  const void* vals = d_in[2];
  const int* idx = (const int*)d_in[3];
  const float* alpha = (const float*)d_in[4];
  float* out = (float*)d_out;
  f16* Wl = (f16*)d_ws;                                   // linear W_eff
  f16* Xs = (f16*)((char*)d_ws + 2 * 1024 * 1024 + 4096); // linear f16 X

  int M = in_sizes[0] / IN_F;              // 32768
  int total = (M * IN_F) / 8;              // 8-f16 chunks

  prep_base<<<dim3(512), dim3(256), 0, stream>>>(base, Wl);
  prep_scatter<<<dim3((NNZ + 255) / 256), dim3(256), 0, stream>>>(base, vals, idx, alpha, Wl);
  conv_x<<<dim3(2048), dim3(256), 0, stream>>>(X, Xs, total);

  hipError_t e = hipFuncSetAttribute(reinterpret_cast<const void*>(&gemm11),
                                     hipFuncAttributeMaxDynamicSharedMemorySize, 163840);
  if (e == hipSuccess) {
    gemm11<<<dim3((M / 256) * 4), dim3(512), 163840, stream>>>(Xs, Wl, out);
  } else {
    (void)hipFuncSetAttribute(reinterpret_cast<const void*>(&gemm10),
                              hipFuncAttributeMaxDynamicSharedMemorySize, 131072);
    gemm10<<<dim3((M / 256) * 4), dim3(512), 131072, stream>>>(Xs, Wl, out);
  }
}